// Round 2
// baseline (676.734 us; speedup 1.0000x reference)
//
#include <hip/hip_runtime.h>
#include <stdint.h>

// Problem constants (fixed by setup_inputs).
constexpr int NPTS = 8192;
constexpr int DIM  = 64;
constexpr int KNN  = 12;

// Tiling: 64x64 output tile per WG (4 waves, each a 32x32 MFMA tile).
constexpr int RT = 64;               // rows per workgroup
constexpr int CT = 64;               // cols per chunk
constexpr int CS = 4;                // column splits (grid parallelism)
constexpr int STRIPE = NPTS / CS;    // 2048 cols per split
constexpr int NCHUNK = STRIPE / CT;  // 32 chunks
constexpr int LSTR = 72;             // LDS row stride in ushorts (144 B: 16B-aligned,
                                     // 2-way bank aliasing only = free per m136)

constexpr unsigned long long SENTINEL = 0xFFFFFFFFFFFFFFFFull;

typedef short bf16x8 __attribute__((ext_vector_type(8)));
typedef float f32x4  __attribute__((ext_vector_type(4)));

__device__ __forceinline__ unsigned short f2bf(float x) {  // RNE truncate f32->bf16
  unsigned u = __float_as_uint(x);
  return (unsigned short)((u + 0x7FFFu + ((u >> 16) & 1u)) >> 16);
}
__device__ __forceinline__ float bf2f(unsigned short h) {
  return __uint_as_float(((unsigned)h) << 16);
}

__global__ void init_out(float* out) {
  if (threadIdx.x < 4) out[threadIdx.x] = 0.0f;  // d_out is poisoned each call
}

// sq[i] = sum_d latent[i][d]^2  (fp32, exact)
__global__ __launch_bounds__(256) void sq_kernel(const float* __restrict__ latent,
                                                 float* __restrict__ sq) {
  int i = blockIdx.x * 256 + threadIdx.x;
  const float4* p = reinterpret_cast<const float4*>(latent + (size_t)i * DIM);
  float s = 0.f;
#pragma unroll
  for (int t = 0; t < DIM / 4; ++t) {
    float4 v = p[t];
    s += v.x * v.x + v.y * v.y + v.z * v.z + v.w * v.w;
  }
  sq[i] = s;
}

// Sorted-ascending 12-list insert; cand packs (d2_bits<<32)|j so u64 compare
// == (value, index) lexicographic == JAX stable argsort order.
__device__ __forceinline__ void topk_insert(unsigned long long cand,
                                            unsigned long long pk[KNN]) {
#pragma unroll
  for (int s = KNN - 1; s >= 0; --s) {
    bool belongs = cand < pk[s];
    bool shift = (s > 0) && (cand < pk[s - 1]);
    unsigned long long nv = shift ? pk[s - 1] : cand;
    if (belongs) pk[s] = nv;
  }
}

__global__ __launch_bounds__(256, 2) void dz_main(
    const float* __restrict__ latent, const float* __restrict__ latent_norm,
    const float* __restrict__ dist_X, const float* __restrict__ mask_X,
    const float* __restrict__ sq, unsigned long long* __restrict__ topk_ws,
    float* __restrict__ d_out) {
  // hi/lo bf16 split tiles, k contiguous per row (MFMA frag = 8 consecutive k).
  __shared__ unsigned short Ah[RT * LSTR], Al[RT * LSTR];
  __shared__ unsigned short Bh[CT * LSTR], Bl[CT * LSTR];
  __shared__ unsigned long long buf[RT * CT];  // per-row candidate queues
  __shared__ int   cnt[RT];
  __shared__ float thr[RT];  // running 12th-smallest d2 per row
  __shared__ float sqA[RT];
  __shared__ float sqB[CT];
  __shared__ float red[256];

  const int tid = threadIdx.x;
  const int tile = blockIdx.x / CS;
  const int split = blockIdx.x % CS;
  const int ib = tile * RT;
  const int jb0 = split * STRIPE;

  const int wid = tid >> 6;          // wave id 0..3
  const int lane = tid & 63;
  const int quad = lane >> 4;        // 0..3
  const int l16 = lane & 15;
  const int wr = wid >> 1;           // wave row-block (32 rows)
  const int wc = wid & 1;            // wave col-block (32 cols)

  const float invnorm = 1.0f / latent_norm[0];

  // Stage A tile once: fp32 -> (hi,lo) bf16, row-major k-contiguous.
#pragma unroll
  for (int i = 0; i < (RT * DIM) / (256 * 4); ++i) {  // 4 float4 per thread
    int flat = i * 256 + tid;        // [0,1024): 64 rows x 16 float4
    int r = flat >> 4, kq = flat & 15;
    float4 v = *reinterpret_cast<const float4*>(latent + (size_t)(ib + r) * DIM + kq * 4);
    ushort4 h, l;
    h.x = f2bf(v.x); l.x = f2bf(v.x - bf2f(h.x));
    h.y = f2bf(v.y); l.y = f2bf(v.y - bf2f(h.y));
    h.z = f2bf(v.z); l.z = f2bf(v.z - bf2f(h.z));
    h.w = f2bf(v.w); l.w = f2bf(v.w - bf2f(h.w));
    *reinterpret_cast<ushort4*>(&Ah[r * LSTR + kq * 4]) = h;
    *reinterpret_cast<ushort4*>(&Al[r * LSTR + kq * 4]) = l;
  }
  if (tid < RT) { sqA[tid] = sq[ib + tid]; thr[tid] = 3.4e38f; }

  unsigned long long pk[KNN];
#pragma unroll
  for (int t = 0; t < KNN; ++t) pk[t] = SENTINEL;

  float acc1 = 0.f;  // distance1_2 partial

  for (int ch = 0; ch < NCHUNK; ++ch) {
    const int jb = jb0 + ch * CT;
    __syncthreads();  // (A) prev merge done; Bh/Bl/buf/cnt safe to overwrite

    // Stage B tile: fp32 -> (hi,lo) bf16.
#pragma unroll
    for (int i = 0; i < (CT * DIM) / (256 * 4); ++i) {
      int flat = i * 256 + tid;
      int c = flat >> 4, kq = flat & 15;
      float4 v = *reinterpret_cast<const float4*>(latent + (size_t)(jb + c) * DIM + kq * 4);
      ushort4 h, l;
      h.x = f2bf(v.x); l.x = f2bf(v.x - bf2f(h.x));
      h.y = f2bf(v.y); l.y = f2bf(v.y - bf2f(h.y));
      h.z = f2bf(v.z); l.z = f2bf(v.z - bf2f(h.z));
      h.w = f2bf(v.w); l.w = f2bf(v.w - bf2f(h.w));
      *reinterpret_cast<ushort4*>(&Bh[c * LSTR + kq * 4]) = h;
      *reinterpret_cast<ushort4*>(&Bl[c * LSTR + kq * 4]) = l;
    }
    if (tid < CT) sqB[tid] = sq[jb + tid];
    if (tid < RT) cnt[tid] = 0;
    __syncthreads();  // (B)

    // Gram via split-bf16 MFMA: hi*hi + hi*lo + lo*hi (~5e-6 rel err on d2).
    f32x4 acc[2][2];
#pragma unroll
    for (int rb = 0; rb < 2; ++rb)
#pragma unroll
      for (int cb = 0; cb < 2; ++cb) acc[rb][cb] = (f32x4){0.f, 0.f, 0.f, 0.f};

#pragma unroll
    for (int kk = 0; kk < 2; ++kk) {  // K=64 in two K=32 MFMA steps
      const int ko = kk * 32 + quad * 8;
      bf16x8 ah[2], al[2], bh[2], bl[2];
#pragma unroll
      for (int rb = 0; rb < 2; ++rb) {
        int row = wr * 32 + rb * 16 + l16;
        ah[rb] = *reinterpret_cast<const bf16x8*>(&Ah[row * LSTR + ko]);
        al[rb] = *reinterpret_cast<const bf16x8*>(&Al[row * LSTR + ko]);
      }
#pragma unroll
      for (int cb = 0; cb < 2; ++cb) {
        int col = wc * 32 + cb * 16 + l16;
        bh[cb] = *reinterpret_cast<const bf16x8*>(&Bh[col * LSTR + ko]);
        bl[cb] = *reinterpret_cast<const bf16x8*>(&Bl[col * LSTR + ko]);
      }
#pragma unroll
      for (int rb = 0; rb < 2; ++rb)
#pragma unroll
        for (int cb = 0; cb < 2; ++cb) {
          acc[rb][cb] = __builtin_amdgcn_mfma_f32_16x16x32_bf16(ah[rb], bh[cb], acc[rb][cb], 0, 0, 0);
          acc[rb][cb] = __builtin_amdgcn_mfma_f32_16x16x32_bf16(ah[rb], bl[cb], acc[rb][cb], 0, 0, 0);
          acc[rb][cb] = __builtin_amdgcn_mfma_f32_16x16x32_bf16(al[rb], bh[cb], acc[rb][cb], 0, 0, 0);
        }
    }

    // Epilogue: d2, distance1_2 (mask-gated dist_X gather), candidate push.
    // C/D layout (verified): col = lane&15, row = quad*4 + reg.
#pragma unroll
    for (int rb = 0; rb < 2; ++rb) {
#pragma unroll
      for (int cb = 0; cb < 2; ++cb) {
        const int row0 = wr * 32 + rb * 16 + quad * 4;
        const int col_l = wc * 32 + cb * 16 + l16;
        const int gj = jb + col_l;
        const float sqb = sqB[col_l];
        // Prefetch the 4 mask values (4 rows, same col).
        float mv[4];
#pragma unroll
        for (int r = 0; r < 4; ++r)
          mv[r] = mask_X[(size_t)(ib + row0 + r) * NPTS + gj];
#pragma unroll
        for (int r = 0; r < 4; ++r) {
          const int rl = row0 + r;
          const int gi = ib + rl;
          float d2 = sqA[rl] + sqb - 2.0f * acc[rb][cb][r];
          float d2c = fmaxf(d2, 0.0f);
          float dz = (d2c > 0.0f) ? sqrtf(d2c) * invnorm : 0.0f;
          if (mv[r] != 0.0f) {  // ~0.15% of lanes: gather dist_X only here
            float dx = dist_X[(size_t)gi * NPTS + gj];
            float diff = dx - dz;
            acc1 += mv[r] * diff * diff;
          }
          if (d2c < thr[rl] && gj != gi) {
            int pos = atomicAdd(&cnt[rl], 1);  // LDS atomic; pos < CT guaranteed
            buf[rl * CT + pos] =
                ((unsigned long long)__float_as_uint(d2c) << 32) | (unsigned)gj;
          }
        }
      }
    }
    __syncthreads();  // (C) pushes visible

    if (tid < RT) {  // one thread per row merges its (rare) candidates
      int n = cnt[tid];
      for (int t = 0; t < n; ++t) {
        unsigned long long cand = buf[tid * CT + t];
        if (cand < pk[KNN - 1]) topk_insert(cand, pk);
      }
      thr[tid] = __uint_as_float((unsigned)(pk[KNN - 1] >> 32));
    }
  }

  // Per-(row,split) partial top-12 to workspace.
  if (tid < RT) {
    size_t base = ((size_t)(ib + tid) * CS + split) * KNN;
#pragma unroll
    for (int t = 0; t < KNN; ++t) topk_ws[base + t] = pk[t];
  }

  // Block-reduce distance1_2 partials.
  red[tid] = acc1;
  __syncthreads();
  for (int s = 128; s > 0; s >>= 1) {
    if (tid < s) red[tid] += red[tid + s];
    __syncthreads();
  }
  if (tid == 0) {
    atomicAdd(&d_out[2], red[0]);
    atomicAdd(&d_out[0], red[0]);
  }
}

// Merge the CS partial top-12 lists per row, gather edges, accumulate
// distance2_1 and the matched-edge count.
__global__ __launch_bounds__(256) void finalize_kernel(
    const float* __restrict__ latent_norm, const float* __restrict__ dist_X,
    const float* __restrict__ mask_X,
    const unsigned long long* __restrict__ topk_ws, float* __restrict__ d_out) {
  __shared__ float red[256];
  const int tid = threadIdx.x;
  const int gi = blockIdx.x * 256 + tid;
  const float invnorm = 1.0f / latent_norm[0];

  unsigned long long pk[KNN];
#pragma unroll
  for (int t = 0; t < KNN; ++t) pk[t] = SENTINEL;

  const unsigned long long* src = topk_ws + (size_t)gi * CS * KNN;
  for (int t = 0; t < CS * KNN; ++t) {
    unsigned long long cand = src[t];
    if (cand < pk[KNN - 1]) topk_insert(cand, pk);
  }

  float acc2 = 0.f, accc = 0.f;
#pragma unroll
  for (int t = 0; t < KNN; ++t) {
    unsigned j = (unsigned)(pk[t] & 0xFFFFFFFFull);
    float d2 = __uint_as_float((unsigned)(pk[t] >> 32));
    float dz = (d2 > 0.0f) ? sqrtf(d2) * invnorm : 0.0f;
    float dxv = dist_X[(size_t)gi * NPTS + j];
    float mxv = mask_X[(size_t)gi * NPTS + j];
    float diff = dxv - dz;
    acc2 += diff * diff;
    accc += mxv;  // Z-edge also present in X-mask
  }

  red[tid] = acc2;
  __syncthreads();
  for (int s = 128; s > 0; s >>= 1) {
    if (tid < s) red[tid] += red[tid + s];
    __syncthreads();
  }
  float racc2 = red[0];
  __syncthreads();
  red[tid] = accc;
  __syncthreads();
  for (int s = 128; s > 0; s >>= 1) {
    if (tid < s) red[tid] += red[tid + s];
    __syncthreads();
  }
  if (tid == 0) {
    atomicAdd(&d_out[3], racc2);
    atomicAdd(&d_out[0], racc2);
    atomicAdd(&d_out[1], red[0] * (1.0f / ((float)NPTS * (float)KNN)));
  }
}

extern "C" void kernel_launch(void* const* d_in, const int* in_sizes, int n_in,
                              void* d_out, int out_size, void* d_ws,
                              size_t ws_size, hipStream_t stream) {
  const float* latent      = (const float*)d_in[0];
  const float* latent_norm = (const float*)d_in[1];
  const float* dist_X      = (const float*)d_in[2];
  const float* mask_X      = (const float*)d_in[3];
  // d_in[4] = k (always 12; compiled in as KNN)
  float* out = (float*)d_out;

  float* sq = (float*)d_ws;                                   // 8192 floats
  unsigned long long* topk =
      (unsigned long long*)((char*)d_ws + NPTS * sizeof(float));  // 3.1 MB

  init_out<<<1, 64, 0, stream>>>(out);
  sq_kernel<<<NPTS / 256, 256, 0, stream>>>(latent, sq);
  dz_main<<<(NPTS / RT) * CS, 256, 0, stream>>>(latent, latent_norm, dist_X,
                                                mask_X, sq, topk, out);
  finalize_kernel<<<NPTS / 256, 256, 0, stream>>>(latent_norm, dist_X, mask_X,
                                                  topk, out);
}

// Round 3
// 663.446 us; speedup vs baseline: 1.0200x; 1.0200x over previous
//
#include <hip/hip_runtime.h>
#include <stdint.h>

// Problem constants (fixed by setup_inputs).
constexpr int NPTS = 8192;
constexpr int DIM  = 64;
constexpr int KNN  = 12;

// Tiling: 64x64 output tile per WG (4 waves, each a 32x32 MFMA tile).
constexpr int RT = 64;               // rows per workgroup
constexpr int CT = 64;               // cols per chunk
constexpr int CS = 4;                // column splits (grid parallelism)
constexpr int STRIPE = NPTS / CS;    // 2048 cols per split
constexpr int NCHUNK = STRIPE / CT;  // 32 chunks
constexpr int LSTR = 72;             // LDS row stride in ushorts (144 B = 9*16:
                                     // b128-aligned, 2-way bank alias only = free)

constexpr unsigned long long SENTINEL = 0xFFFFFFFFFFFFFFFFull;

typedef short bf16x8 __attribute__((ext_vector_type(8)));
typedef float f32x4  __attribute__((ext_vector_type(4)));

__device__ __forceinline__ unsigned short f2bf(float x) {  // RNE f32->bf16
  unsigned u = __float_as_uint(x);
  return (unsigned short)((u + 0x7FFFu + ((u >> 16) & 1u)) >> 16);
}
__device__ __forceinline__ float bf2f(unsigned short h) {
  return __uint_as_float(((unsigned)h) << 16);
}

// Zero d_out (poisoned every call) and the per-row edge counters.
__global__ __launch_bounds__(256) void init_kernel(float* out, int* ecnt) {
  int g = blockIdx.x * 256 + threadIdx.x;
  if (g < NPTS) ecnt[g] = 0;
  if (g < 4) out[g] = 0.0f;
}

// latent fp32 -> (hi,lo) bf16 split arrays + row sumsq. One thread per row.
__global__ __launch_bounds__(256) void conv_kernel(
    const float* __restrict__ latent, unsigned short* __restrict__ Lh,
    unsigned short* __restrict__ Ll, float* __restrict__ sq) {
  int i = blockIdx.x * 256 + threadIdx.x;
  const float4* p = reinterpret_cast<const float4*>(latent + (size_t)i * DIM);
  float s = 0.f;
#pragma unroll
  for (int t = 0; t < DIM / 4; ++t) {
    float4 v = p[t];
    s += v.x * v.x + v.y * v.y + v.z * v.z + v.w * v.w;
    ushort4 h, l;
    h.x = f2bf(v.x); l.x = f2bf(v.x - bf2f(h.x));
    h.y = f2bf(v.y); l.y = f2bf(v.y - bf2f(h.y));
    h.z = f2bf(v.z); l.z = f2bf(v.z - bf2f(h.z));
    h.w = f2bf(v.w); l.w = f2bf(v.w - bf2f(h.w));
    *reinterpret_cast<ushort4*>(Lh + (size_t)i * DIM + t * 4) = h;
    *reinterpret_cast<ushort4*>(Ll + (size_t)i * DIM + t * 4) = l;
  }
  sq[i] = s;
}

// Stream mask_X coalesced at full BW; compress to per-row edge lists
// (col index + dist_X value). Exactly KNN nonzeros per row by construction.
__global__ __launch_bounds__(256) void scan_mask(
    const float* __restrict__ mask_X, const float* __restrict__ dist_X,
    int* __restrict__ ecnt, int* __restrict__ ecol, float* __restrict__ edx) {
  const int total4 = NPTS * NPTS / 4;
  int stride = gridDim.x * 256;
  for (int idx4 = blockIdx.x * 256 + threadIdx.x; idx4 < total4; idx4 += stride) {
    float4 m = reinterpret_cast<const float4*>(mask_X)[idx4];
    if (m.x == 0.f && m.y == 0.f && m.z == 0.f && m.w == 0.f) continue;
    int base = idx4 * 4;
    float mv[4] = {m.x, m.y, m.z, m.w};
#pragma unroll
    for (int c = 0; c < 4; ++c) {
      if (mv[c] != 0.f) {
        int pos = base + c;
        int i = pos >> 13, j = pos & (NPTS - 1);
        int slot = atomicAdd(&ecnt[i], 1);
        if (slot < KNN) {
          ecol[i * KNN + slot] = j;
          edx[i * KNN + slot] = dist_X[pos];
        }
      }
    }
  }
}

// Sorted-ascending 12-list insert; cand packs (d2_bits<<32)|j so u64 compare
// == (value, index) lexicographic == JAX stable argsort order.
__device__ __forceinline__ void topk_insert(unsigned long long cand,
                                            unsigned long long pk[KNN]) {
#pragma unroll
  for (int s = KNN - 1; s >= 0; --s) {
    bool belongs = cand < pk[s];
    bool shift = (s > 0) && (cand < pk[s - 1]);
    unsigned long long nv = shift ? pk[s - 1] : cand;
    if (belongs) pk[s] = nv;
  }
}

// Pure Gram + top-k. No dense global streams: only the 4 MB bf16 hi/lo
// latent (L2/L3-resident) is read.
__global__ __launch_bounds__(256, 2) void dz_main(
    const unsigned short* __restrict__ Lh, const unsigned short* __restrict__ Ll,
    const float* __restrict__ sq, unsigned long long* __restrict__ topk_ws) {
  __shared__ unsigned short Ah[RT * LSTR], Al[RT * LSTR];
  __shared__ unsigned short Bh[CT * LSTR], Bl[CT * LSTR];
  __shared__ unsigned long long buf[RT * CT];  // per-row candidate queues
  __shared__ int   cnt[RT];
  __shared__ float thr[RT];  // running 12th-smallest d2 per row
  __shared__ float sqA[RT];
  __shared__ float sqB[CT];

  const int tid = threadIdx.x;
  const int tile = blockIdx.x / CS;
  const int split = blockIdx.x % CS;
  const int ib = tile * RT;
  const int jb0 = split * STRIPE;

  const int wid = tid >> 6;
  const int lane = tid & 63;
  const int quad = lane >> 4;
  const int l16 = lane & 15;
  const int wr = wid >> 1;
  const int wc = wid & 1;

  // Stage A tile once: pure uint4 copies (64 rows x 8 chunks of 16B).
#pragma unroll
  for (int it = 0; it < 2; ++it) {
    int f = it * 256 + tid;          // 0..511
    int r = f >> 3, c = f & 7;
    const uint4* sh = reinterpret_cast<const uint4*>(Lh + (size_t)(ib + r) * DIM + c * 8);
    const uint4* sl = reinterpret_cast<const uint4*>(Ll + (size_t)(ib + r) * DIM + c * 8);
    *reinterpret_cast<uint4*>(&Ah[r * LSTR + c * 8]) = *sh;
    *reinterpret_cast<uint4*>(&Al[r * LSTR + c * 8]) = *sl;
  }
  if (tid < RT) { sqA[tid] = sq[ib + tid]; thr[tid] = 3.4e38f; }

  unsigned long long pk[KNN];
#pragma unroll
  for (int t = 0; t < KNN; ++t) pk[t] = SENTINEL;

  for (int ch = 0; ch < NCHUNK; ++ch) {
    const int jb = jb0 + ch * CT;
    __syncthreads();  // (A) prev merge done; Bh/Bl/buf/cnt safe to overwrite
#pragma unroll
    for (int it = 0; it < 2; ++it) {
      int f = it * 256 + tid;
      int r = f >> 3, c = f & 7;
      const uint4* sh = reinterpret_cast<const uint4*>(Lh + (size_t)(jb + r) * DIM + c * 8);
      const uint4* sl = reinterpret_cast<const uint4*>(Ll + (size_t)(jb + r) * DIM + c * 8);
      *reinterpret_cast<uint4*>(&Bh[r * LSTR + c * 8]) = *sh;
      *reinterpret_cast<uint4*>(&Bl[r * LSTR + c * 8]) = *sl;
    }
    if (tid < CT) sqB[tid] = sq[jb + tid];
    if (tid < RT) cnt[tid] = 0;
    __syncthreads();  // (B)

    // Gram via split-bf16 MFMA: hi*hi + hi*lo + lo*hi (~5e-6 rel err on d2).
    f32x4 acc[2][2];
#pragma unroll
    for (int rb = 0; rb < 2; ++rb)
#pragma unroll
      for (int cb = 0; cb < 2; ++cb) acc[rb][cb] = (f32x4){0.f, 0.f, 0.f, 0.f};

#pragma unroll
    for (int kk = 0; kk < 2; ++kk) {  // K=64 in two K=32 MFMA steps
      const int ko = kk * 32 + quad * 8;
      bf16x8 ah[2], al[2], bh[2], bl[2];
#pragma unroll
      for (int rb = 0; rb < 2; ++rb) {
        int row = wr * 32 + rb * 16 + l16;
        ah[rb] = *reinterpret_cast<const bf16x8*>(&Ah[row * LSTR + ko]);
        al[rb] = *reinterpret_cast<const bf16x8*>(&Al[row * LSTR + ko]);
      }
#pragma unroll
      for (int cb = 0; cb < 2; ++cb) {
        int col = wc * 32 + cb * 16 + l16;
        bh[cb] = *reinterpret_cast<const bf16x8*>(&Bh[col * LSTR + ko]);
        bl[cb] = *reinterpret_cast<const bf16x8*>(&Bl[col * LSTR + ko]);
      }
#pragma unroll
      for (int rb = 0; rb < 2; ++rb)
#pragma unroll
        for (int cb = 0; cb < 2; ++cb) {
          acc[rb][cb] = __builtin_amdgcn_mfma_f32_16x16x32_bf16(ah[rb], bh[cb], acc[rb][cb], 0, 0, 0);
          acc[rb][cb] = __builtin_amdgcn_mfma_f32_16x16x32_bf16(ah[rb], bl[cb], acc[rb][cb], 0, 0, 0);
          acc[rb][cb] = __builtin_amdgcn_mfma_f32_16x16x32_bf16(al[rb], bh[cb], acc[rb][cb], 0, 0, 0);
        }
    }

    // Epilogue: d2 + candidate push only (no sqrt, no global traffic).
    // C/D layout (verified): col = lane&15, row = quad*4 + reg.
#pragma unroll
    for (int rb = 0; rb < 2; ++rb) {
      const int row0 = wr * 32 + rb * 16 + quad * 4;
#pragma unroll
      for (int r = 0; r < 4; ++r) {
        const int rl = row0 + r;
        const int gi = ib + rl;
        const float sa = sqA[rl];
        const float t_thr = thr[rl];
#pragma unroll
        for (int cb = 0; cb < 2; ++cb) {
          const int col_l = wc * 32 + cb * 16 + l16;
          const int gj = jb + col_l;
          float d2 = sa + sqB[col_l] - 2.0f * acc[rb][cb][r];
          float d2c = fmaxf(d2, 0.0f);
          if (d2c < t_thr && gj != gi) {
            int pos = atomicAdd(&cnt[rl], 1);  // pos < CT guaranteed (cap=64)
            buf[rl * CT + pos] =
                ((unsigned long long)__float_as_uint(d2c) << 32) | (unsigned)gj;
          }
        }
      }
    }
    __syncthreads();  // (C) pushes visible

    if (tid < RT) {  // one thread per row merges its (rare) candidates
      int n = cnt[tid];
      for (int t = 0; t < n; ++t) {
        unsigned long long cand = buf[tid * CT + t];
        if (cand < pk[KNN - 1]) topk_insert(cand, pk);
      }
      thr[tid] = __uint_as_float((unsigned)(pk[KNN - 1] >> 32));
    }
  }

  // Per-(row,split) partial top-12 to workspace.
  if (tid < RT) {
    size_t base = ((size_t)(ib + tid) * CS + split) * KNN;
#pragma unroll
    for (int t = 0; t < KNN; ++t) topk_ws[base + t] = pk[t];
  }
}

// distance1_2 over the 98K X-edges: dz from an exact fp32 dot on latent.
__global__ __launch_bounds__(256) void sig1_kernel(
    const float* __restrict__ latent, const float* __restrict__ latent_norm,
    const int* __restrict__ ecol, const float* __restrict__ edx,
    float* __restrict__ d_out) {
  __shared__ float red[256];
  const int tid = threadIdx.x;
  const int e = blockIdx.x * 256 + tid;  // e < NPTS*KNN exactly
  const float invnorm = 1.0f / latent_norm[0];

  int i = e / KNN;
  int j = ecol[e];
  float dx = edx[e];
  const float4* a = reinterpret_cast<const float4*>(latent + (size_t)i * DIM);
  const float4* b = reinterpret_cast<const float4*>(latent + (size_t)j * DIM);
  float d2 = 0.f;
#pragma unroll
  for (int t = 0; t < DIM / 4; ++t) {
    float4 va = a[t], vb = b[t];
    float ex = va.x - vb.x, ey = va.y - vb.y, ez = va.z - vb.z, ew = va.w - vb.w;
    d2 += ex * ex + ey * ey + ez * ez + ew * ew;
  }
  float dz = (d2 > 0.f) ? sqrtf(d2) * invnorm : 0.f;
  float diff = dx - dz;
  float acc = diff * diff;

  red[tid] = acc;
  __syncthreads();
  for (int s = 128; s > 0; s >>= 1) {
    if (tid < s) red[tid] += red[tid + s];
    __syncthreads();
  }
  if (tid == 0) {
    atomicAdd(&d_out[2], red[0]);
    atomicAdd(&d_out[0], red[0]);
  }
}

// Merge the CS partial top-12 lists per row; distance2_1 + matched count.
__global__ __launch_bounds__(256) void finalize_kernel(
    const float* __restrict__ latent_norm, const float* __restrict__ dist_X,
    const int* __restrict__ ecol, const unsigned long long* __restrict__ topk_ws,
    float* __restrict__ d_out) {
  __shared__ float red[256];
  const int tid = threadIdx.x;
  const int gi = blockIdx.x * 256 + tid;
  const float invnorm = 1.0f / latent_norm[0];

  unsigned long long pk[KNN];
#pragma unroll
  for (int t = 0; t < KNN; ++t) pk[t] = SENTINEL;

  const unsigned long long* src = topk_ws + (size_t)gi * CS * KNN;
  for (int t = 0; t < CS * KNN; ++t) {
    unsigned long long cand = src[t];
    if (cand < pk[KNN - 1]) topk_insert(cand, pk);
  }

  int ec[KNN];
#pragma unroll
  for (int t = 0; t < KNN; ++t) ec[t] = ecol[gi * KNN + t];

  float acc2 = 0.f, accc = 0.f;
#pragma unroll
  for (int t = 0; t < KNN; ++t) {
    int j = (int)(unsigned)(pk[t] & 0xFFFFFFFFull);
    float d2 = __uint_as_float((unsigned)(pk[t] >> 32));
    float dz = (d2 > 0.0f) ? sqrtf(d2) * invnorm : 0.0f;
    float dxv = dist_X[(size_t)gi * NPTS + j];
    float diff = dxv - dz;
    acc2 += diff * diff;
    int hit = 0;
#pragma unroll
    for (int s = 0; s < KNN; ++s) hit |= (ec[s] == j);
    accc += (float)hit;  // Z-edge also present in X-mask
  }

  red[tid] = acc2;
  __syncthreads();
  for (int s = 128; s > 0; s >>= 1) {
    if (tid < s) red[tid] += red[tid + s];
    __syncthreads();
  }
  float racc2 = red[0];
  __syncthreads();
  red[tid] = accc;
  __syncthreads();
  for (int s = 128; s > 0; s >>= 1) {
    if (tid < s) red[tid] += red[tid + s];
    __syncthreads();
  }
  if (tid == 0) {
    atomicAdd(&d_out[3], racc2);
    atomicAdd(&d_out[0], racc2);
    atomicAdd(&d_out[1], red[0] * (1.0f / ((float)NPTS * (float)KNN)));
  }
}

extern "C" void kernel_launch(void* const* d_in, const int* in_sizes, int n_in,
                              void* d_out, int out_size, void* d_ws,
                              size_t ws_size, hipStream_t stream) {
  const float* latent      = (const float*)d_in[0];
  const float* latent_norm = (const float*)d_in[1];
  const float* dist_X      = (const float*)d_in[2];
  const float* mask_X      = (const float*)d_in[3];
  float* out = (float*)d_out;

  // Workspace layout (all 16B-aligned).
  char* w = (char*)d_ws;
  float*          sq   = (float*)w;                    w += NPTS * 4;            // 32 KB
  unsigned short* Lh   = (unsigned short*)w;           w += NPTS * DIM * 2;      // 1 MB
  unsigned short* Ll   = (unsigned short*)w;           w += NPTS * DIM * 2;      // 1 MB
  int*            ecnt = (int*)w;                      w += NPTS * 4;            // 32 KB
  int*            ecol = (int*)w;                      w += NPTS * KNN * 4;      // 384 KB
  float*          edx  = (float*)w;                    w += NPTS * KNN * 4;      // 384 KB
  unsigned long long* topk = (unsigned long long*)w;   // 3 MB

  init_kernel<<<NPTS / 256, 256, 0, stream>>>(out, ecnt);
  conv_kernel<<<NPTS / 256, 256, 0, stream>>>(latent, Lh, Ll, sq);
  scan_mask<<<2048, 256, 0, stream>>>(mask_X, dist_X, ecnt, ecol, edx);
  dz_main<<<(NPTS / RT) * CS, 256, 0, stream>>>(Lh, Ll, sq, topk);
  sig1_kernel<<<NPTS * KNN / 256, 256, 0, stream>>>(latent, latent_norm, ecol,
                                                    edx, out);
  finalize_kernel<<<NPTS / 256, 256, 0, stream>>>(latent_norm, dist_X, ecol,
                                                  topk, out);
}